// Round 7
// baseline (52.448 us; speedup 1.0000x reference)
//
#include <hip/hip_runtime.h>
#include <hip/hip_bf16.h>

#define NE 9
#define NDIM 1024
#define BM 64
#define BN 64
#define BK 64
#define NT (NDIM / BK)      // 16
#define NSLOT_MAX 72        // sum ceil(cnt_e/64) <= 64 + 8
#define WPX 144             // work items per XCD = NSLOT_MAX*16/8

typedef __attribute__((ext_vector_type(8))) short bf16x8;
typedef __attribute__((ext_vector_type(4))) float f32x4;

__device__ __forceinline__ unsigned pack2_bf16(float a, float b) {
    __hip_bfloat162 h = __float22bfloat162_rn(float2{a, b});
    return *reinterpret_cast<unsigned*>(&h);
}

__device__ __forceinline__ void gload_lds16(const void* g, void* l) {
    __builtin_amdgcn_global_load_lds(
        (const __attribute__((address_space(1))) unsigned int*)g,
        (__attribute__((address_space(3))) unsigned int*)l, 16, 0, 0);
}

// ------- fused prep: bucket + desc table (block 0) | W f32->bf16 (blocks 1+) -------
__global__ __launch_bounds__(256)
void prep_kernel(const float* __restrict__ W, const int* __restrict__ sidx,
                 unsigned short* __restrict__ Wb,
                 int* __restrict__ perm, int4* __restrict__ desc, int nB) {
    if (blockIdx.x == 0) {
        __shared__ int cnt[NE];
        __shared__ int cur[NE];
        int t = threadIdx.x;
        if (t < NE) cnt[t] = 0;
        __syncthreads();
        for (int i = t; i < nB; i += 256) atomicAdd(&cnt[sidx[i]], 1);
        __syncthreads();
        if (t == 0) {
            int run = 0, s = 0;
            for (int e = 0; e < NE; ++e) {
                cur[e] = run;
                int c = cnt[e];
                for (int m0 = 0; m0 < c; m0 += BM) {
                    desc[s] = make_int4(e, run + m0, min(BM, c - m0), 0);
                    ++s;
                }
                run += c;
            }
            for (; s < NSLOT_MAX; ++s) desc[s] = make_int4(-1, 0, 1, 0);
        }
        __syncthreads();
        for (int i = t; i < nB; i += 256) {
            int p = atomicAdd(&cur[sidx[i]], 1);
            perm[p] = i;
        }
    } else {
        const int NW8 = NE * NDIM * (NDIM / 8);   // 1,179,648 8-float units
        const int stride = (gridDim.x - 1) * 256;
        for (int u = (blockIdx.x - 1) * 256 + threadIdx.x; u < NW8; u += stride) {
            const float4* src = (const float4*)W + 2 * (size_t)u;
            float4 a = src[0], c = src[1];
            uint4 o;
            o.x = pack2_bf16(a.x, a.y);
            o.y = pack2_bf16(a.z, a.w);
            o.z = pack2_bf16(c.x, c.y);
            o.w = pack2_bf16(c.z, c.w);
            ((uint4*)Wb)[u] = o;
        }
    }
}

// ------- grouped GEMM: 64x64 tiles, 4 waves (2x2, 32x32 each), 32 KB LDS ----------
// A: f32 gather from x, reg-stage + cvt + swizzled ds_write (issued early).
// B: global_load_lds from bf16 Wb, source column pre-swizzled, LDS linear.
__global__ __launch_bounds__(256, 4)
void gemm_kernel(const float* __restrict__ x,
                 const unsigned short* __restrict__ Wb,
                 const float* __restrict__ bias,
                 const int* __restrict__ perm,
                 const int4* __restrict__ desc,
                 float* __restrict__ out) {
    // static bijective XCD partition: XCD = b&7 owns 9 contiguous slots x 16 N
    const int b    = blockIdx.x;
    const int w    = (b & 7) * WPX + (b >> 3);
    const int slot = w >> 4;
    const int n    = w & 15;
    const int4 d   = desc[slot];          // single 16B descriptor load
    if (d.x < 0) return;
    const int e = d.x, rowstart = d.y, rcnt = d.z;
    const int n0 = n * BN;

    // ushort-indexed LDS: A0@0 A1@4096 B0@8192 B1@12288 (32 KB)
    __shared__ __align__(16) unsigned short lds[16384];

    const int t    = threadIdx.x;
    const int wave = t >> 6;
    const int lane = t & 63;
    const int fr   = lane & 15;
    const int fq   = lane >> 4;
    const int wr   = (wave >> 1) * 32;   // wave M-origin
    const int wc   = (wave & 1) * 32;    // wave N-origin
    const int xr   = fr & 7;             // read-side swizzle key

    // staging decomposition: thread t covers octet c8 of rows srow and srow+32
    const int srow = t >> 3;             // 0..31
    const int c8   = t & 7;              // K-octet (8 elems)
    const int sc   = c8 ^ (srow & 7);    // swizzled octet (key same for srow+32)

    int lm0 = srow;      if (lm0 >= rcnt) lm0 = rcnt - 1;   // clamp; masked at store
    int lm1 = srow + 32; if (lm1 >= rcnt) lm1 = rcnt - 1;
    const float* ap0 = x + (size_t)perm[rowstart + lm0] * NDIM + c8 * 8;
    const float* ap1 = x + (size_t)perm[rowstart + lm1] * NDIM + c8 * 8;
    // B source: pre-swizzled column sc*8 of W rows (n0+srow), (n0+srow+32)
    const unsigned short* bp =
        Wb + ((size_t)e * NDIM + n0 + srow) * NDIM + sc * 8;

    float4 av[4];

#define LOADA(K0)                                                              \
    do {                                                                       \
        av[0] = *(const float4*)(ap0 + (K0));                                  \
        av[1] = *(const float4*)(ap0 + (K0) + 4);                              \
        av[2] = *(const float4*)(ap1 + (K0));                                  \
        av[3] = *(const float4*)(ap1 + (K0) + 4);                              \
    } while (0)

#define CVTA(BUF)                                                              \
    do {                                                                       \
        uint4 o0, o1;                                                          \
        o0.x = pack2_bf16(av[0].x, av[0].y);                                   \
        o0.y = pack2_bf16(av[0].z, av[0].w);                                   \
        o0.z = pack2_bf16(av[1].x, av[1].y);                                   \
        o0.w = pack2_bf16(av[1].z, av[1].w);                                   \
        o1.x = pack2_bf16(av[2].x, av[2].y);                                   \
        o1.y = pack2_bf16(av[2].z, av[2].w);                                   \
        o1.z = pack2_bf16(av[3].x, av[3].y);                                   \
        o1.w = pack2_bf16(av[3].z, av[3].w);                                   \
        *reinterpret_cast<uint4*>(&lds[(BUF) * 4096 + srow * 64 + sc * 8]) = o0;      \
        *reinterpret_cast<uint4*>(&lds[(BUF) * 4096 + (srow + 32) * 64 + sc * 8]) = o1;\
    } while (0)

#define STAGEB(BUF, K0)                                                        \
    do {                                                                       \
        gload_lds16(bp + (K0), &lds[8192 + (BUF) * 4096 + wave * 512]);        \
        gload_lds16(bp + (size_t)32 * NDIM + (K0),                             \
                    &lds[8192 + (BUF) * 4096 + 2048 + wave * 512]);            \
    } while (0)

    f32x4 acc[2][2];
#pragma unroll
    for (int i = 0; i < 2; ++i)
#pragma unroll
        for (int k = 0; k < 2; ++k) acc[i][k] = (f32x4)(0.0f);

    // prologue: tile 0 fully staged; tile 1 A-loads in flight
    LOADA(0);
    STAGEB(0, 0);
    CVTA(0);
    LOADA(BK);
    __syncthreads();

    for (int tt = 0; tt < NT; ++tt) {
        const int cur = tt & 1;
        // issue next tile's B DMA first; it flies under this tile's compute
        if (tt + 1 < NT) STAGEB(cur ^ 1, (tt + 1) * BK);

        const int abase = cur * 4096;
        const int bbase = 8192 + cur * 4096;
#pragma unroll
        for (int kk = 0; kk < 2; ++kk) {
            const int cs = ((kk * 4 + fq) ^ xr) * 8;
            bf16x8 af[2], bfv[2];
#pragma unroll
            for (int mf = 0; mf < 2; ++mf)
                af[mf] = *reinterpret_cast<const bf16x8*>(
                    &lds[abase + (wr + mf * 16 + fr) * 64 + cs]);
#pragma unroll
            for (int nf = 0; nf < 2; ++nf)
                bfv[nf] = *reinterpret_cast<const bf16x8*>(
                    &lds[bbase + (wc + nf * 16 + fr) * 64 + cs]);
#pragma unroll
            for (int mf = 0; mf < 2; ++mf)
#pragma unroll
                for (int nf = 0; nf < 2; ++nf)
                    acc[mf][nf] = __builtin_amdgcn_mfma_f32_16x16x32_bf16(
                        af[mf], bfv[nf], acc[mf][nf], 0, 0, 0);
        }

        if (tt + 1 < NT) {
            CVTA(cur ^ 1);                       // av = tile tt+1 (loaded early)
            if (tt + 2 < NT) LOADA((tt + 2) * BK);  // next A loads fly past barrier
            __syncthreads();
        }
    }
#undef LOADA
#undef CVTA
#undef STAGEB

    // ---- epilogue: bias add + scatter store via perm ----
    float bl[2];
#pragma unroll
    for (int nf = 0; nf < 2; ++nf)
        bl[nf] = bias[e * NDIM + n0 + wc + nf * 16 + fr];

#pragma unroll
    for (int mf = 0; mf < 2; ++mf) {
#pragma unroll
        for (int jr = 0; jr < 4; ++jr) {
            int lm = wr + mf * 16 + fq * 4 + jr;
            if (lm < rcnt) {
                int grow = perm[rowstart + lm];
                float* orow = out + (size_t)grow * NDIM;
#pragma unroll
                for (int nf = 0; nf < 2; ++nf)
                    orow[n0 + wc + nf * 16 + fr] = acc[mf][nf][jr] + bl[nf];
            }
        }
    }
}

// ---------------- tiny correct fallback (ws too small; not expected) --------------
__global__ void naive_kernel(const float* __restrict__ x, const float* __restrict__ W,
                             const float* __restrict__ bias,
                             const int* __restrict__ sidx, float* __restrict__ out,
                             int nB) {
    int i = blockIdx.x;
    int c = threadIdx.x + (blockIdx.y << 8);
    if (i >= nB || c >= NDIM) return;
    int e = sidx[i];
    const float* wrow = W + ((size_t)e * NDIM + c) * NDIM;
    const float* xr = x + (size_t)i * NDIM;
    float s = bias[e * NDIM + c];
    for (int k = 0; k < NDIM; ++k) s += xr[k] * wrow[k];
    out[(size_t)i * NDIM + c] = s;
}

extern "C" void kernel_launch(void* const* d_in, const int* in_sizes, int n_in,
                              void* d_out, int out_size, void* d_ws, size_t ws_size,
                              hipStream_t stream) {
    const float* x    = (const float*)d_in[0];
    const float* W    = (const float*)d_in[1];
    const float* bias = (const float*)d_in[2];
    const int*   sidx = (const int*)d_in[3];
    float*       out  = (float*)d_out;

    const int nB = in_sizes[3];   // 4096

    char* wsb = (char*)d_ws;
    size_t p_desc = (size_t)nB * 4;                          // perm first
    size_t p_wb   = ((p_desc + NSLOT_MAX * 16 + 511) / 512) * 512;
    size_t need   = p_wb + (size_t)NE * NDIM * NDIM * 2;

    if (ws_size < need) {
        dim3 g(nB, NDIM / 256);
        naive_kernel<<<g, 256, 0, stream>>>(x, W, bias, sidx, out, nB);
        return;
    }

    int*  perm = (int*)wsb;
    int4* desc = (int4*)(wsb + p_desc);
    unsigned short* Wb = (unsigned short*)(wsb + p_wb);

    prep_kernel<<<1024, 256, 0, stream>>>(W, sidx, Wb, perm, desc, nB);

    gemm_kernel<<<NSLOT_MAX * 16, 256, 0, stream>>>(x, Wb, bias, perm, desc, out);
}